// Round 3
// baseline (160.507 us; speedup 1.0000x reference)
//
#include <hip/hip_runtime.h>
#include <hip/hip_bf16.h>

#define N_ROWS 4096
#define TWO_N 8192
#define DIM 512
#define INV_T 14.285714285714286f           // 1/0.07
#define LOG2E 1.4426950408889634f
#define C_LOG2E 20.60992915555662f          // (1/0.07)*log2(e)
#define INV_SQRT_T 3.7796447300922722f      // 1/sqrt(0.07)

typedef __bf16 bf16x8 __attribute__((ext_vector_type(8)));
typedef float f32x4 __attribute__((ext_vector_type(4)));

#define ASYNC_COPY16(gp, lp)                                                     \
  __builtin_amdgcn_global_load_lds((const __attribute__((address_space(1))) void*)(gp), \
                                   (__attribute__((address_space(3))) void*)(lp), 16, 0, 0)

#define VMCNT(n) asm volatile("s_waitcnt vmcnt(" #n ")" ::: "memory")

// Wave-per-row prep: float4 loads, butterfly shuffle reduce (no LDS/sync),
// 16B bf16x8 stores. 1024 blocks x 4 waves = 4096 rows; also zeroes rowsum.
__global__ __launch_bounds__(256) void k_prep(const float* __restrict__ z1,
                                              const float* __restrict__ z2,
                                              __hip_bfloat16* __restrict__ zn,
                                              float* __restrict__ posbuf,
                                              float* __restrict__ rowsum) {
  const int t = threadIdx.x;
  const int wv = t >> 6, lane = t & 63;
  const int r = blockIdx.x * 4 + wv;
  if (blockIdx.x < 32) rowsum[blockIdx.x * 256 + t] = 0.f;   // 32*256 = 8192

  const float4* p1 = reinterpret_cast<const float4*>(z1 + (size_t)r * DIM) + (lane << 1);
  const float4* p2 = reinterpret_cast<const float4*>(z2 + (size_t)r * DIM) + (lane << 1);
  float4 a0 = p1[0], a1 = p1[1];
  float4 b0 = p2[0], b1 = p2[1];

  float s1 = a0.x * a0.x + a0.y * a0.y + a0.z * a0.z + a0.w * a0.w
           + a1.x * a1.x + a1.y * a1.y + a1.z * a1.z + a1.w * a1.w;
  float s2 = b0.x * b0.x + b0.y * b0.y + b0.z * b0.z + b0.w * b0.w
           + b1.x * b1.x + b1.y * b1.y + b1.z * b1.z + b1.w * b1.w;
  float sd = a0.x * b0.x + a0.y * b0.y + a0.z * b0.z + a0.w * b0.w
           + a1.x * b1.x + a1.y * b1.y + a1.z * b1.z + a1.w * b1.w;
#pragma unroll
  for (int off = 1; off < 64; off <<= 1) {
    s1 += __shfl_xor(s1, off, 64);
    s2 += __shfl_xor(s2, off, 64);
    sd += __shfl_xor(sd, off, 64);
  }
  const float sc1 = INV_SQRT_T / fmaxf(sqrtf(s1), 1e-8f);
  const float sc2 = INV_SQRT_T / fmaxf(sqrtf(s2), 1e-8f);

  bf16x8 o;
  o[0] = (__bf16)(a0.x * sc1); o[1] = (__bf16)(a0.y * sc1);
  o[2] = (__bf16)(a0.z * sc1); o[3] = (__bf16)(a0.w * sc1);
  o[4] = (__bf16)(a1.x * sc1); o[5] = (__bf16)(a1.y * sc1);
  o[6] = (__bf16)(a1.z * sc1); o[7] = (__bf16)(a1.w * sc1);
  *reinterpret_cast<bf16x8*>(zn + (size_t)r * DIM + (lane << 3)) = o;

  o[0] = (__bf16)(b0.x * sc2); o[1] = (__bf16)(b0.y * sc2);
  o[2] = (__bf16)(b0.z * sc2); o[3] = (__bf16)(b0.w * sc2);
  o[4] = (__bf16)(b1.x * sc2); o[5] = (__bf16)(b1.y * sc2);
  o[6] = (__bf16)(b1.z * sc2); o[7] = (__bf16)(b1.w * sc2);
  *reinterpret_cast<bf16x8*>(zn + (size_t)(r + N_ROWS) * DIM + (lane << 3)) = o;

  if (lane == 0) posbuf[r] = sd * sc1 * sc2;   // = cos(z1_r,z2_r)/T
}

// ---------------------------------------------------------------------------
// 256x256-tile, 8-wave, BK=64, 4-phase-per-K-tile flash-LSE GEMM over the
// upper-triangle 32x32 tile grid (528 blocks). Port of the verified 8-phase
// template: per phase {8x ds_read_b128, stage global_load_lds, s_barrier,
// lgkmcnt(0), setprio(1), 16x MFMA, setprio(0), [vmcnt], s_barrier}.
// LDS 128KiB = 2 K-tile buffers x (A 32KB + B 32KB). Per-wave output 128x64
// (43.7 FLOP/LDS-byte vs 32 before -> LDS pipe no longer dominates MFMA).
//
// Swizzle (both-sides, rule #21): LDS slot s (16B granules) of a tile half
// holds logical granule (row = s>>3, g = (s&7) ^ (row&7)). Staging keeps the
// LDS dest linear (wave-uniform base + lane*16) and pre-swizzles the GLOBAL
// source granule; the ds_read applies the same XOR. Fragment reads then hit
// each bank exactly 8x (the b128 floor) -- conflict-optimal.
// ---------------------------------------------------------------------------
__global__ __launch_bounds__(512, 2) void k_lse(const __hip_bfloat16* __restrict__ Zn,
                                                float* __restrict__ rowsum) {
  __shared__ char smem[131072] __attribute__((aligned(16)));
  const int tid  = threadIdx.x;
  const int wave = tid >> 6;
  const int lane = tid & 63;
  const int cl   = lane & 15;
  const int q    = lane >> 4;
  const int wm   = wave >> 2;      // 0..1: row half (128 rows)
  const int wn   = wave & 3;       // 0..3: col quarter (64 cols)

  // bijective XCD swizzle (528 = 8*66), then linear -> (rt, ct), rt <= ct, NT=32
  const int b = (blockIdx.x & 7) * 66 + (blockIdx.x >> 3);
  int rt = (int)((65.0f - sqrtf(4225.0f - 8.0f * (float)b)) * 0.5f);
  if (rt < 0) rt = 0;
  if (rt > 31) rt = 31;
  while (rt > 0 && 32 * rt - rt * (rt - 1) / 2 > b) rt--;
  while (32 * (rt + 1) - (rt + 1) * rt / 2 <= b) rt++;
  const int ct = rt + (b - (32 * rt - rt * (rt - 1) / 2));

  // staging: thread owns slots tid + 512c (c=0..3) of each 2048-granule half.
  // slot s -> row s>>3, stored granule g = (s&7) ^ ((s>>3)&7).
  const int r0 = tid >> 3;                          // 0..63
  const int gg = (tid & 7) ^ ((tid >> 3) & 7);      // granule index 0..7
  const __hip_bfloat16* gA = Zn + (size_t)(rt * 256 + r0) * DIM + gg * 8;
  const __hip_bfloat16* gB = Zn + (size_t)(ct * 256 + r0) * DIM + gg * 8;

  // fragment-read byte bases: addr = base + i*2048 (+ mh*8192) XOR kc*64
  const int xa = ((q ^ (cl & 7)) << 4);
  const int aBase = (wm * 128 + cl) * 128 + xa;           // A at buffer + 0
  const int bBase = 32768 + (wn * 64 + cl) * 128 + xa;    // B at buffer + 32768

  f32x4 acc[8][4] = {};

#define STAGE_A(d, kt1)                                                         \
  ASYNC_COPY16(gA + (kt1) * 64,             smem + (d) * 65536 + wave * 1024);          \
  ASYNC_COPY16(gA + (kt1) * 64 + 64 * DIM,  smem + (d) * 65536 + wave * 1024 + 8192);   \
  ASYNC_COPY16(gA + (kt1) * 64 + 128 * DIM, smem + (d) * 65536 + wave * 1024 + 16384);  \
  ASYNC_COPY16(gA + (kt1) * 64 + 192 * DIM, smem + (d) * 65536 + wave * 1024 + 24576)

#define STAGE_B(d, kt1)                                                         \
  ASYNC_COPY16(gB + (kt1) * 64,             smem + (d) * 65536 + 32768 + wave * 1024);          \
  ASYNC_COPY16(gB + (kt1) * 64 + 64 * DIM,  smem + (d) * 65536 + 32768 + wave * 1024 + 8192);   \
  ASYNC_COPY16(gB + (kt1) * 64 + 128 * DIM, smem + (d) * 65536 + 32768 + wave * 1024 + 16384);  \
  ASYNC_COPY16(gB + (kt1) * 64 + 192 * DIM, smem + (d) * 65536 + 32768 + wave * 1024 + 24576)

#define PHASE(d, mh, kc, EXTRA1, EXTRA2)                                        \
  {                                                                             \
    const char* _sb = smem + (d) * 65536;                                       \
    bf16x8 af[4], bv[4];                                                        \
    _Pragma("unroll") for (int i = 0; i < 4; i++)                               \
      af[i] = *reinterpret_cast<const bf16x8*>(                                 \
          _sb + ((aBase + (mh) * 8192 + i * 2048) ^ ((kc) * 64)));              \
    _Pragma("unroll") for (int j = 0; j < 4; j++)                               \
      bv[j] = *reinterpret_cast<const bf16x8*>(                                 \
          _sb + ((bBase + j * 2048) ^ ((kc) * 64)));                            \
    EXTRA1;                                                                     \
    __builtin_amdgcn_s_barrier();                                               \
    asm volatile("s_waitcnt lgkmcnt(0)" ::: "memory");                          \
    __builtin_amdgcn_sched_barrier(0);                                          \
    __builtin_amdgcn_s_setprio(1);                                              \
    _Pragma("unroll") for (int i = 0; i < 4; i++)                               \
      _Pragma("unroll") for (int j = 0; j < 4; j++)                             \
        acc[(mh) * 4 + i][j] = __builtin_amdgcn_mfma_f32_16x16x32_bf16(         \
            af[i], bv[j], acc[(mh) * 4 + i][j], 0, 0, 0);                       \
    __builtin_amdgcn_s_setprio(0);                                              \
    EXTRA2;                                                                     \
    __builtin_amdgcn_s_barrier();                                               \
  }

  // prologue: stage K-tile 0 into buffer 0, full drain once.
  STAGE_A(0, 0);
  STAGE_B(0, 0);
  VMCNT(0);
  __builtin_amdgcn_s_barrier();

#pragma unroll
  for (int it = 0; it < 4; ++it) {
    const int khi = 2 * it + 1;          // compile-time (loop fully unrolled)
    // K-tile 2it in buf0; stage K-tile khi -> buf1 during phases 1-2.
    PHASE(0, 0, 0, STAGE_A(1, khi), );
    PHASE(0, 0, 1, STAGE_B(1, khi), );
    PHASE(0, 1, 0, , );
    PHASE(0, 1, 1, , VMCNT(0));
    // K-tile khi in buf1; stage K-tile khi+1 -> buf0 (except last iteration).
    if (it < 3) {
      PHASE(1, 0, 0, STAGE_A(0, khi + 1), );
      PHASE(1, 0, 1, STAGE_B(0, khi + 1), );
      PHASE(1, 1, 0, , );
      PHASE(1, 1, 1, , VMCNT(0));
    } else {
      PHASE(1, 0, 0, , );
      PHASE(1, 0, 1, , );
      PHASE(1, 1, 0, , );
      PHASE(1, 1, 1, , );
    }
  }
#undef PHASE
#undef STAGE_A
#undef STAGE_B

  // Epilogue: e = exp(s - C), diagonal masked. C-frag layout: col = cl,
  // row = q*4 + r. Wave covers rows rt*256 + wm*128 + I*16 + q*4 + r,
  // cols ct*256 + wn*64 + j*16 + cl.
  const bool dt = (rt == ct);
  float psum[8][4];
#pragma unroll
  for (int i = 0; i < 8; i++)
#pragma unroll
    for (int r = 0; r < 4; r++) psum[i][r] = 0.f;
  float colp[4] = {0.f, 0.f, 0.f, 0.f};

#pragma unroll
  for (int i = 0; i < 8; i++)
#pragma unroll
    for (int j = 0; j < 4; j++)
#pragma unroll
      for (int r = 0; r < 4; r++) {
        float e = exp2f(fmaf(acc[i][j][r], LOG2E, -C_LOG2E));
        if (dt && (wm * 128 + i * 16 + q * 4 + r) == (wn * 64 + j * 16 + cl)) e = 0.f;
        psum[i][r] += e;
        colp[j] += e;
      }

  // row sums -> rt rows (reduce across cl lanes)
#pragma unroll
  for (int i = 0; i < 8; i++)
#pragma unroll
    for (int r = 0; r < 4; r++) {
      float v = psum[i][r];
      v += __shfl_xor(v, 1, 64);
      v += __shfl_xor(v, 2, 64);
      v += __shfl_xor(v, 4, 64);
      v += __shfl_xor(v, 8, 64);
      if (cl == 0) atomicAdd(&rowsum[rt * 256 + wm * 128 + i * 16 + q * 4 + r], v);
    }

  // col sums -> ct rows (reduce across q lanes), off-diagonal tiles only
  if (!dt) {
#pragma unroll
    for (int j = 0; j < 4; j++) {
      float v = colp[j];
      v += __shfl_xor(v, 16, 64);
      v += __shfl_xor(v, 32, 64);
      if (q == 0) atomicAdd(&rowsum[ct * 256 + wn * 64 + j * 16 + cl], v);
    }
  }
}

// Single-block finalize: 1024 threads, each handles 8 rows.
__global__ void k_final(const float* __restrict__ rowsum, const float* __restrict__ posbuf,
                        float* __restrict__ out) {
  __shared__ float red[16];
  const int t = threadIdx.x;   // 1024 threads
  float s = 0.f;
#pragma unroll
  for (int it = 0; it < TWO_N / 1024; it++) {
    const int row = it * 1024 + t;
    float v = logf(rowsum[row]);
    if (row < N_ROWS) v -= 2.f * posbuf[row];
    s += v;
  }
#pragma unroll
  for (int off = 32; off > 0; off >>= 1) s += __shfl_down(s, off, 64);
  if ((t & 63) == 0) red[t >> 6] = s;
  __syncthreads();
  if (t == 0) {
    float tot = 0.f;
#pragma unroll
    for (int i = 0; i < 16; i++) tot += red[i];
    out[0] = tot / (float)TWO_N + INV_T;
  }
}

extern "C" void kernel_launch(void* const* d_in, const int* in_sizes, int n_in,
                              void* d_out, int out_size, void* d_ws, size_t ws_size,
                              hipStream_t stream) {
  const float* z1 = (const float*)d_in[0];
  const float* z2 = (const float*)d_in[1];
  float* out = (float*)d_out;
  char* ws = (char*)d_ws;

  __hip_bfloat16* zn = (__hip_bfloat16*)ws;              // 8192*512*2 = 8388608 B
  float* rowsum = (float*)(ws + 8388608);                 // 8192*4 = 32768 B
  float* posbuf = (float*)(ws + 8421376);                 // 4096*4 = 16384 B

  k_prep<<<1024, 256, 0, stream>>>(z1, z2, zn, posbuf, rowsum);
  k_lse<<<528, 512, 0, stream>>>(zn, rowsum);
  k_final<<<1, 1024, 0, stream>>>(rowsum, posbuf, out);
}

// Round 4
// 125.329 us; speedup vs baseline: 1.2807x; 1.2807x over previous
//
#include <hip/hip_runtime.h>
#include <hip/hip_bf16.h>

#define N_ROWS 4096
#define TWO_N 8192
#define DIM 512
#define BK 32
#define NKS (DIM / BK)                      // 16 K-steps
#define INV_T 14.285714285714286f           // 1/0.07
#define LOG2E 1.4426950408889634f
#define C_LOG2E 20.60992915555662f          // (1/0.07)*log2(e)
#define INV_SQRT_T 3.7796447300922722f      // 1/sqrt(0.07)

typedef __bf16 bf16x8 __attribute__((ext_vector_type(8)));
typedef float f32x4 __attribute__((ext_vector_type(4)));

#define ASYNC_COPY16(gp, lp)                                                     \
  __builtin_amdgcn_global_load_lds((const __attribute__((address_space(1))) void*)(gp), \
                                   (__attribute__((address_space(3))) void*)(lp), 16, 0, 0)

#define VMCNT(n) asm volatile("s_waitcnt vmcnt(" #n ")" ::: "memory")

// Wave-per-row prep: float4 loads, butterfly shuffle reduce (no LDS/sync),
// 16B bf16x8 stores. 1024 blocks x 4 waves = 4096 rows; also zeroes rowsum.
__global__ __launch_bounds__(256) void k_prep(const float* __restrict__ z1,
                                              const float* __restrict__ z2,
                                              __hip_bfloat16* __restrict__ zn,
                                              float* __restrict__ posbuf,
                                              float* __restrict__ rowsum) {
  const int t = threadIdx.x;
  const int wv = t >> 6, lane = t & 63;
  const int r = blockIdx.x * 4 + wv;
  if (blockIdx.x < 32) rowsum[blockIdx.x * 256 + t] = 0.f;   // 32*256 = 8192

  const float4* p1 = reinterpret_cast<const float4*>(z1 + (size_t)r * DIM) + (lane << 1);
  const float4* p2 = reinterpret_cast<const float4*>(z2 + (size_t)r * DIM) + (lane << 1);
  float4 a0 = p1[0], a1 = p1[1];
  float4 b0 = p2[0], b1 = p2[1];

  float s1 = a0.x * a0.x + a0.y * a0.y + a0.z * a0.z + a0.w * a0.w
           + a1.x * a1.x + a1.y * a1.y + a1.z * a1.z + a1.w * a1.w;
  float s2 = b0.x * b0.x + b0.y * b0.y + b0.z * b0.z + b0.w * b0.w
           + b1.x * b1.x + b1.y * b1.y + b1.z * b1.z + b1.w * b1.w;
  float sd = a0.x * b0.x + a0.y * b0.y + a0.z * b0.z + a0.w * b0.w
           + a1.x * b1.x + a1.y * b1.y + a1.z * b1.z + a1.w * b1.w;
#pragma unroll
  for (int off = 1; off < 64; off <<= 1) {
    s1 += __shfl_xor(s1, off, 64);
    s2 += __shfl_xor(s2, off, 64);
    sd += __shfl_xor(sd, off, 64);
  }
  const float sc1 = INV_SQRT_T / fmaxf(sqrtf(s1), 1e-8f);
  const float sc2 = INV_SQRT_T / fmaxf(sqrtf(s2), 1e-8f);

  bf16x8 o;
  o[0] = (__bf16)(a0.x * sc1); o[1] = (__bf16)(a0.y * sc1);
  o[2] = (__bf16)(a0.z * sc1); o[3] = (__bf16)(a0.w * sc1);
  o[4] = (__bf16)(a1.x * sc1); o[5] = (__bf16)(a1.y * sc1);
  o[6] = (__bf16)(a1.z * sc1); o[7] = (__bf16)(a1.w * sc1);
  *reinterpret_cast<bf16x8*>(zn + (size_t)r * DIM + (lane << 3)) = o;

  o[0] = (__bf16)(b0.x * sc2); o[1] = (__bf16)(b0.y * sc2);
  o[2] = (__bf16)(b0.z * sc2); o[3] = (__bf16)(b0.w * sc2);
  o[4] = (__bf16)(b1.x * sc2); o[5] = (__bf16)(b1.y * sc2);
  o[6] = (__bf16)(b1.z * sc2); o[7] = (__bf16)(b1.w * sc2);
  *reinterpret_cast<bf16x8*>(zn + (size_t)(r + N_ROWS) * DIM + (lane << 3)) = o;

  if (lane == 0) posbuf[r] = sd * sc1 * sc2;   // = cos(z1_r,z2_r)/T
}

// ---------------------------------------------------------------------------
// Flash-LSE GEMM, r2 loop skeleton (counted vmcnt, 3 LDS buffers, one barrier
// per K-step) with TWO column-tiles per block: block computes (rt,ctA) and
// (rt,ctA+1) sharing the A-tile. Wave tile 64x128 (acc[4][8]): 32 MFMA per
// 12 ds_read_b128 per iter (FLOP/LDS-byte 2.0 -> 2.67), per-CU block-iters
// 130 -> 66, A staging traffic halved. 1056 blocks (8x132, XCD-bijective).
//
// Conflict-free LDS swizzle (r3-proven, 0 conflicts): 16B granule of logical
// (row, kg) stored at slot row*4 + (kg ^ ((row>>1)&3)). Staging keeps LDS
// dest linear (slot = tid) and pre-swizzles the GLOBAL source granule
// kg0 = (tid&3)^((tid>>3)&3); ds_read applies the same XOR -> every 16-lane
// batch hits all 8 bank quads (r2's rotation hit only 2 -> 4.26M conflicts).
//
// LDS buffer d at smem + d*24576: A [0,8K), B_A [8K,16K), B_B [16K,24K).
// Odd rows of the tile-triangle leave one phantom sub-tile: staged from a
// safe address (ctA), MFMA'd, results discarded in the epilogue (hasB).
// ---------------------------------------------------------------------------
__global__ __launch_bounds__(256, 2) void k_lse(const __hip_bfloat16* __restrict__ Zn,
                                                float* __restrict__ rowsum) {
  __shared__ char smem[73728] __attribute__((aligned(16)));
  const int tid  = threadIdx.x;
  const int wave = tid >> 6;
  const int lane = tid & 63;
  const int cl   = lane & 15;
  const int q    = lane >> 4;

  // XCD-bijective swizzle: 1056 = 8 * 132.
  const int b = (blockIdx.x & 7) * 132 + (blockIdx.x >> 3);

  // row rt (0..63) has m = 64-rt tiles, paired adjacently: h = (65-rt)>>1
  // pair-blocks. cum(rt) = t*(65-t) + (rt&1 ? 32-t : 0), t = rt>>1.
#define CUM(r) (((r) >> 1) * (65 - ((r) >> 1)) + (((r) & 1) ? (32 - ((r) >> 1)) : 0))
  int rt = 65 - (int)sqrtf(4225.0f - 4.0f * (float)b);
  if (rt < 0) rt = 0;
  if (rt > 63) rt = 63;
  while (rt > 0 && CUM(rt) > b) rt--;
  while (rt < 63 && CUM(rt + 1) <= b) rt++;
  const int k = b - CUM(rt);
#undef CUM
  const int ctA = rt + 2 * k;
  const int ctB = ctA + 1;
  const bool hasB = (ctB < 64);
  const int ctBs = hasB ? ctB : ctA;        // safe staging source

  const int wr = (wave >> 1) * 64;   // wave's row offset in A-tile
  const int wc = (wave & 1) * 64;    // wave's col offset within each B-tile

  // staging: thread owns slots tid, tid+256 of each 128x32 tile (512 granules)
  const int r0  = tid >> 2;                         // 0..63
  const int kg0 = (tid & 3) ^ ((tid >> 3) & 3);     // pre-swizzled granule
  const __hip_bfloat16* gA0  = Zn + (size_t)(rt * 128 + r0) * DIM + kg0 * 8;
  const __hip_bfloat16* gBA0 = Zn + (size_t)(ctA * 128 + r0) * DIM + kg0 * 8;
  const __hip_bfloat16* gBB0 = Zn + (size_t)(ctBs * 128 + r0) * DIM + kg0 * 8;

  f32x4 acc[4][8] = {};
  // fragment-read byte offset within a row: same XOR as the store side
  const int kxl = (q ^ ((cl >> 1) & 3)) << 4;

#define STAGE(d, ks1)                                                       \
  {                                                                         \
    char* _b = smem + (d) * 24576 + wave * 1024;                            \
    const int _ko = (ks1) * BK;                                             \
    ASYNC_COPY16(gA0 + _ko,             _b);                                \
    ASYNC_COPY16(gA0 + _ko + 64 * DIM,  _b + 4096);                         \
    ASYNC_COPY16(gBA0 + _ko,            _b + 8192);                         \
    ASYNC_COPY16(gBA0 + _ko + 64 * DIM, _b + 12288);                        \
    ASYNC_COPY16(gBB0 + _ko,            _b + 16384);                        \
    ASYNC_COPY16(gBB0 + _ko + 64 * DIM, _b + 20480);                        \
  }

  STAGE(0, 0);
  STAGE(1, 1);
#pragma unroll
  for (int ks = 0; ks < NKS; ks++) {
    const int cur = ks % 3;
    // wait for buf[cur]'s 6 loads (issued 2 iterations ago); the newest 6
    // (next buffer) stay in flight. Full drain only on the last iteration.
    if (ks + 1 < NKS) { VMCNT(6); } else { VMCNT(0); }
    __builtin_amdgcn_s_barrier();
    asm volatile("" ::: "memory");
    if (ks + 2 < NKS) STAGE((ks + 2) % 3, ks + 2);

    const char* sA  = smem + cur * 24576;
    const char* sB0 = sA + 8192;
    const char* sB1 = sA + 16384;
    bf16x8 af[4], bfr[8];
#pragma unroll
    for (int i = 0; i < 4; i++)
      af[i] = *reinterpret_cast<const bf16x8*>(sA + (wr + i * 16 + cl) * 64 + kxl);
#pragma unroll
    for (int j = 0; j < 4; j++) {
      bfr[j]     = *reinterpret_cast<const bf16x8*>(sB0 + (wc + j * 16 + cl) * 64 + kxl);
      bfr[4 + j] = *reinterpret_cast<const bf16x8*>(sB1 + (wc + j * 16 + cl) * 64 + kxl);
    }
    __builtin_amdgcn_s_setprio(1);
#pragma unroll
    for (int i = 0; i < 4; i++)
#pragma unroll
      for (int j = 0; j < 8; j++)
        acc[i][j] = __builtin_amdgcn_mfma_f32_16x16x32_bf16(af[i], bfr[j], acc[i][j], 0, 0, 0);
    __builtin_amdgcn_s_setprio(0);
  }
#undef STAGE

  // Epilogue: e = exp(s - C), diagonal masked (only possible in sub-tile A,
  // since rt == ctA requires k == 0; ctB > rt always).
  // C-frag layout: col = cl, row = q*4 + r within 16x16 frag (i,j).
  const bool diagw = (rt == ctA) && (wr == wc);
  float psum[4][4];
#pragma unroll
  for (int i = 0; i < 4; i++)
#pragma unroll
    for (int r = 0; r < 4; r++) psum[i][r] = 0.f;
  float colpA[4] = {0.f, 0.f, 0.f, 0.f};
  float colpB[4] = {0.f, 0.f, 0.f, 0.f};

#pragma unroll
  for (int i = 0; i < 4; i++)
#pragma unroll
    for (int j = 0; j < 4; j++)
#pragma unroll
      for (int r = 0; r < 4; r++) {
        float e = exp2f(fmaf(acc[i][j][r], LOG2E, -C_LOG2E));
        if (diagw && (i == j) && (cl == q * 4 + r)) e = 0.f;
        psum[i][r] += e;
        colpA[j] += e;
      }
  if (hasB) {
#pragma unroll
    for (int i = 0; i < 4; i++)
#pragma unroll
      for (int j = 0; j < 4; j++)
#pragma unroll
        for (int r = 0; r < 4; r++) {
          float e = exp2f(fmaf(acc[i][4 + j][r], LOG2E, -C_LOG2E));
          psum[i][r] += e;
          colpB[j] += e;
        }
  }

  // row sums -> rt rows (reduce across cols: cl lanes)
#pragma unroll
  for (int i = 0; i < 4; i++)
#pragma unroll
    for (int r = 0; r < 4; r++) {
      float v = psum[i][r];
      v += __shfl_xor(v, 1, 64);
      v += __shfl_xor(v, 2, 64);
      v += __shfl_xor(v, 4, 64);
      v += __shfl_xor(v, 8, 64);
      if (cl == 0) atomicAdd(&rowsum[rt * 128 + wr + i * 16 + q * 4 + r], v);
    }

  // col sums -> ctA rows (off-diagonal only) and ctB rows (always off-diag)
  if (rt != ctA) {
#pragma unroll
    for (int j = 0; j < 4; j++) {
      float v = colpA[j];
      v += __shfl_xor(v, 16, 64);
      v += __shfl_xor(v, 32, 64);
      if (q == 0) atomicAdd(&rowsum[ctA * 128 + wc + j * 16 + cl], v);
    }
  }
  if (hasB) {
#pragma unroll
    for (int j = 0; j < 4; j++) {
      float v = colpB[j];
      v += __shfl_xor(v, 16, 64);
      v += __shfl_xor(v, 32, 64);
      if (q == 0) atomicAdd(&rowsum[ctB * 128 + wc + j * 16 + cl], v);
    }
  }
}

// Single-block finalize: 1024 threads, each handles 8 rows.
__global__ void k_final(const float* __restrict__ rowsum, const float* __restrict__ posbuf,
                        float* __restrict__ out) {
  __shared__ float red[16];
  const int t = threadIdx.x;   // 1024 threads
  float s = 0.f;
#pragma unroll
  for (int it = 0; it < TWO_N / 1024; it++) {
    const int row = it * 1024 + t;
    float v = logf(rowsum[row]);
    if (row < N_ROWS) v -= 2.f * posbuf[row];
    s += v;
  }
#pragma unroll
  for (int off = 32; off > 0; off >>= 1) s += __shfl_down(s, off, 64);
  if ((t & 63) == 0) red[t >> 6] = s;
  __syncthreads();
  if (t == 0) {
    float tot = 0.f;
#pragma unroll
    for (int i = 0; i < 16; i++) tot += red[i];
    out[0] = tot / (float)TWO_N + INV_T;
  }
}

extern "C" void kernel_launch(void* const* d_in, const int* in_sizes, int n_in,
                              void* d_out, int out_size, void* d_ws, size_t ws_size,
                              hipStream_t stream) {
  const float* z1 = (const float*)d_in[0];
  const float* z2 = (const float*)d_in[1];
  float* out = (float*)d_out;
  char* ws = (char*)d_ws;

  __hip_bfloat16* zn = (__hip_bfloat16*)ws;              // 8192*512*2 = 8388608 B
  float* rowsum = (float*)(ws + 8388608);                 // 8192*4 = 32768 B
  float* posbuf = (float*)(ws + 8421376);                 // 4096*4 = 16384 B

  k_prep<<<1024, 256, 0, stream>>>(z1, z2, zn, posbuf, rowsum);
  k_lse<<<1056, 256, 0, stream>>>(zn, rowsum);
  k_final<<<1, 1024, 0, stream>>>(rowsum, posbuf, out);
}